// Round 6
// baseline (2888.979 us; speedup 1.0000x reference)
//
#include <hip/hip_runtime.h>
#include <hip/hip_fp16.h>
#include <math.h>

constexpr int BATCH = 8192;
constexpr int DIN   = 1024;
constexpr int DH    = 512;
constexpr int DOUT  = 512;
constexpr int STEPS = 30;

typedef __attribute__((ext_vector_type(8))) _Float16 f16x8;   // 4 VGPRs
typedef __attribute__((ext_vector_type(2))) _Float16 f16x2_t; // 1 VGPR
typedef __attribute__((ext_vector_type(4))) float f32x4;

__device__ __forceinline__ float fast_tanh(float x) {
  return 1.0f - 2.0f / (1.0f + __expf(2.0f * x));
}

// ---------------------------------------------------------------------------
// Spectral norm (split for coalescing)
// ---------------------------------------------------------------------------
__global__ void sigma_k1(const float* __restrict__ W,
                         const float* __restrict__ u,
                         float* __restrict__ v) {
  const int j = threadIdx.x;           // 512
  const int i0 = blockIdx.x * 8;       // 64 blocks
  float acc = 0.0f;
  #pragma unroll
  for (int i = 0; i < 8; ++i) acc += W[(size_t)(i0 + i) * DH + j] * u[i0 + i];
  atomicAdd(&v[j], acc);
}

__device__ __forceinline__ float block_reduce_sum_512(float x, float* sred) {
  #pragma unroll
  for (int off = 32; off > 0; off >>= 1) x += __shfl_down(x, off, 64);
  int wave = threadIdx.x >> 6, lane = threadIdx.x & 63;
  if (lane == 0) sred[wave] = x;
  __syncthreads();
  float r = 0.0f;
  if (wave == 0) {
    r = (lane < 8) ? sred[lane] : 0.0f;
    #pragma unroll
    for (int off = 4; off > 0; off >>= 1) r += __shfl_down(r, off, 64);
    if (lane == 0) sred[0] = r;
  }
  __syncthreads();
  float res = sred[0];
  __syncthreads();
  return res;
}

__global__ void sigma_k2(const float* __restrict__ W,
                         const float* __restrict__ vg,
                         float* __restrict__ sigma_out) {
  __shared__ __align__(16) float v[DH];
  __shared__ float sred[8];
  const int j = threadIdx.x;  // 512
  float vj = vg[j];
  float nn = block_reduce_sum_512(vj * vj, sred);
  float inv = 1.0f / (sqrtf(nn) + 1e-12f);
  v[j] = vj;
  __syncthreads();
  const float4* R = (const float4*)(W + (size_t)j * DH);
  const float4* V = (const float4*)v;
  float s0 = 0.f, s1 = 0.f, s2 = 0.f, s3 = 0.f;
  for (int q = 0; q < DH / 4; q += 4) {
    float4 r0 = R[q], r1 = R[q + 1], r2 = R[q + 2], r3 = R[q + 3];
    float4 v0 = V[q], v1 = V[q + 1], v2 = V[q + 2], v3 = V[q + 3];
    s0 += r0.x * v0.x + r0.y * v0.y + r0.z * v0.z + r0.w * v0.w;
    s1 += r1.x * v1.x + r1.y * v1.y + r1.z * v1.z + r1.w * v1.w;
    s2 += r2.x * v2.x + r2.y * v2.y + r2.z * v2.z + r2.w * v2.w;
    s3 += r3.x * v3.x + r3.y * v3.y + r3.z * v3.z + r3.w * v3.w;
  }
  float wi = ((s0 + s1) + (s2 + s3)) * inv;
  float ww = block_reduce_sum_512(wi * wi, sred);
  if (j == 0) sigma_out[0] = ww / (sqrtf(ww) + 1e-12f);
}

__global__ void f32_to_f16(const float* __restrict__ in,
                           _Float16* __restrict__ out, int n) {
  int i = blockIdx.x * 256 + threadIdx.x;
  if (i < n) out[i] = (_Float16)in[i];
}

// Fragment-linear Wsn: Wf[g][kt][lane][j] = (W[n][k]/sigma) f16,
// n = g*16 + (lane&15), k = kt*32 + (lane>>4)*8 + j.  g<32, kt<16.
__global__ void build_wf(const float* __restrict__ W,
                         const float* __restrict__ sigma,
                         _Float16* __restrict__ Wf) {
  int t = blockIdx.x * 256 + threadIdx.x;  // t < 32768
  int lane = t & 63, kt = (t >> 6) & 15, g = t >> 10;
  int n  = g * 16 + (lane & 15);
  int k0 = kt * 32 + (lane >> 4) * 8;
  float inv = 1.0f / sigma[0];
  #pragma unroll
  for (int j = 0; j < 8; ++j)
    Wf[(size_t)t * 8 + j] = (_Float16)(W[(size_t)n * DH + k0 + j] * inv);
}

// ---------------------------------------------------------------------------
// GEMM (embed / head)
// ---------------------------------------------------------------------------
#define TM 128
#define TN 64
#define BK 64
#define BKP (BK + 8)

enum { MODE_EMBED = 0, MODE_HEAD = 1 };

template <int MODE>
__global__ __launch_bounds__(256, 2) void gemm_fused(
    const _Float16* __restrict__ A, const _Float16* __restrict__ Bw, int K,
    const float* __restrict__ bias1, const float* __restrict__ bias2,
    float* __restrict__ outp) {
  __shared__ __align__(16) _Float16 As[TM][BKP];
  __shared__ __align__(16) _Float16 Bs[TN][BKP];
  const int tid = threadIdx.x, lane = tid & 63, wave = tid >> 6;
  const int wm = wave >> 1, wn = wave & 1;
  const int m0 = blockIdx.x * TM, n0 = blockIdx.y * TN;
  const int l16 = lane & 15, l4 = lane >> 4;

  f32x4 acc[4][2];
  #pragma unroll
  for (int i = 0; i < 4; ++i)
    #pragma unroll
    for (int j = 0; j < 2; ++j) acc[i][j] = (f32x4){0.f, 0.f, 0.f, 0.f};

  for (int k0 = 0; k0 < K; k0 += BK) {
    #pragma unroll
    for (int i = 0; i < 4; ++i) {
      int q = tid + 256 * i, row = q >> 3, col = (q & 7) * 8;
      *reinterpret_cast<uint4*>(&As[row][col]) =
          *reinterpret_cast<const uint4*>(&A[(size_t)(m0 + row) * K + k0 + col]);
    }
    #pragma unroll
    for (int i = 0; i < 2; ++i) {
      int q = tid + 256 * i, row = q >> 3, col = (q & 7) * 8;
      *reinterpret_cast<uint4*>(&Bs[row][col]) =
          *reinterpret_cast<const uint4*>(&Bw[(size_t)(n0 + row) * K + k0 + col]);
    }
    __syncthreads();
    #pragma unroll
    for (int s = 0; s < 2; ++s) {
      f16x8 afrag[4], bfrag[2];
      #pragma unroll
      for (int mi = 0; mi < 4; ++mi)
        afrag[mi] = *reinterpret_cast<const f16x8*>(
            &As[wm * 64 + mi * 16 + l16][s * 32 + l4 * 8]);
      #pragma unroll
      for (int ni = 0; ni < 2; ++ni)
        bfrag[ni] = *reinterpret_cast<const f16x8*>(
            &Bs[wn * 32 + ni * 16 + l16][s * 32 + l4 * 8]);
      #pragma unroll
      for (int mi = 0; mi < 4; ++mi)
        #pragma unroll
        for (int ni = 0; ni < 2; ++ni)
          acc[mi][ni] = __builtin_amdgcn_mfma_f32_16x16x32_f16(
              afrag[mi], bfrag[ni], acc[mi][ni], 0, 0, 0);
    }
    __syncthreads();
  }
  #pragma unroll
  for (int mi = 0; mi < 4; ++mi)
    #pragma unroll
    for (int ni = 0; ni < 2; ++ni)
      #pragma unroll
      for (int r = 0; r < 4; ++r) {
        int gm = m0 + wm * 64 + mi * 16 + l4 * 4 + r;
        int gn = n0 + wn * 32 + ni * 16 + l16;
        size_t idx = (size_t)gm * 512 + gn;
        float s = acc[mi][ni][r];
        outp[idx] = (MODE == MODE_EMBED) ? (s + bias1[gn] + bias2[gn])
                                         : (s + bias1[gn]);
      }
}

// ---------------------------------------------------------------------------
// Persistent recurrence, register-light. 256 blocks x 512 thr (8 waves),
// 1 block/CU. Wave w owns cols [64w,64w+64) = 4 n-tiles, ALL streamed from
// L2 every step (Wsn 512 KB is L2-resident per XCD; depth-1 rolling
// prefetch). NO register-resident weights: rounds 3-5 proved the compiler
// caps arch VGPRs at 128 for 8-wave blocks (unified-file split; launch
// bounds (512,1) and (512,2) both gave VGPR_Count=128) and spills anything
// bigger -> 4.4 GB scratch traffic. This design: ~100 arch VGPRs
// (prefetch 16 + cur 16 + afrag 8 + cc/hr 32 + misc) + acc 32 in AGPRs.
// Cost: per-XCD L2 32 CU x 512 KB/step @ 4.3 TB/s ~= 8.9k cyc/step
// (L2-bound; MFMA 5k cyc/step overlaps underneath).
// ---------------------------------------------------------------------------
__global__ __launch_bounds__(512) void recurrence_persistent(
    const _Float16* __restrict__ Wf,   // [32][16][64][8] frag-linear f16
    const float* __restrict__ c0g,     // [8192][512] f32 (embed output)
    _Float16* __restrict__ hg)         // [8192][512] f16 (final h)
{
  __shared__ _Float16 hhL[32 * 512];   // 32 KB, XOR-swizzled
  __shared__ _Float16 eeL[32 * 512];   // 32 KB, plain
  const int tid  = threadIdx.x;
  const int lane = tid & 63;
  const int w    = tid >> 6;   // 0..7
  const int l16  = lane & 15;
  const int quad = lane >> 4;  // 0..3
  const int row0 = blockIdx.x * 16;  // stripe0; stripe1 = row0 + 4096

  // Streaming base pointers for this wave's 4 n-tiles
  const _Float16* wf0 = Wf + (size_t)(4 * w) * 8192 + lane * 8;
  const _Float16* wf1 = wf0 + 8192;
  const _Float16* wf2 = wf0 + 16384;
  const _Float16* wf3 = wf0 + 24576;

  // Init state: cc = c0, ee = 0.5 c0 (LDS f16), hh1 = 0.5 tanh(c0)
  f16x2_t cc[2][4][2], hr[2][4][2];
  #pragma unroll
  for (int s = 0; s < 2; ++s)
    #pragma unroll
    for (int nt = 0; nt < 4; ++nt)
      #pragma unroll
      for (int r = 0; r < 4; ++r) {
        int lrow = s * 16 + quad * 4 + r;
        int gc   = w * 64 + nt * 16 + l16;
        int grow = row0 + s * 4096 + quad * 4 + r;
        float c0 = c0g[(size_t)grow * 512 + gc];
        cc[s][nt][r >> 1][r & 1] = (_Float16)c0;
        eeL[lrow * 512 + gc] = (_Float16)(0.5f * c0);
        float h1 = 0.5f * fast_tanh(c0);
        hr[s][nt][r >> 1][r & 1] = (_Float16)h1;
        int phys = (gc >> 3) ^ (lrow & 7);
        hhL[lrow * 512 + phys * 8 + (gc & 7)] = (_Float16)h1;
      }
  __syncthreads();

  // 120 GEMM-steps (30 outer x 4; inner step 1 folded since hh_0 = 0)
  #pragma unroll 1
  for (int step = 0; step < 4 * STEPS; ++step) {
    const bool lastS = (step & 3) == 3;
    f32x4 acc[2][4];
    #pragma unroll
    for (int s = 0; s < 2; ++s)
      #pragma unroll
      for (int nt = 0; nt < 4; ++nt) acc[s][nt] = (f32x4){0.f, 0.f, 0.f, 0.f};

    // MFMA phase: all 4 tiles streamed, depth-1 rolling prefetch.
    f16x8 nb0 = *reinterpret_cast<const f16x8*>(wf0);
    f16x8 nb1 = *reinterpret_cast<const f16x8*>(wf1);
    f16x8 nb2 = *reinterpret_cast<const f16x8*>(wf2);
    f16x8 nb3 = *reinterpret_cast<const f16x8*>(wf3);
    #pragma unroll
    for (int kt = 0; kt < 16; ++kt) {
      f16x8 b0 = nb0, b1 = nb1, b2 = nb2, b3 = nb3;
      if (kt < 15) {
        nb0 = *reinterpret_cast<const f16x8*>(wf0 + (kt + 1) * 512);
        nb1 = *reinterpret_cast<const f16x8*>(wf1 + (kt + 1) * 512);
        nb2 = *reinterpret_cast<const f16x8*>(wf2 + (kt + 1) * 512);
        nb3 = *reinterpret_cast<const f16x8*>(wf3 + (kt + 1) * 512);
      }
      #pragma unroll
      for (int s = 0; s < 2; ++s) {
        int lrow = s * 16 + l16;
        int phys = (kt * 4 + quad) ^ (l16 & 7);
        f16x8 af = *reinterpret_cast<const f16x8*>(&hhL[lrow * 512 + phys * 8]);
        acc[s][0] = __builtin_amdgcn_mfma_f32_16x16x32_f16(af, b0, acc[s][0], 0, 0, 0);
        acc[s][1] = __builtin_amdgcn_mfma_f32_16x16x32_f16(af, b1, acc[s][1], 0, 0, 0);
        acc[s][2] = __builtin_amdgcn_mfma_f32_16x16x32_f16(af, b2, acc[s][2], 0, 0, 0);
        acc[s][3] = __builtin_amdgcn_mfma_f32_16x16x32_f16(af, b3, acc[s][3], 0, 0, 0);
      }
    }
    __syncthreads();  // bar1: all hhL reads complete

    // Epilogue + hh writes
    #pragma unroll
    for (int s = 0; s < 2; ++s)
      #pragma unroll
      for (int nt = 0; nt < 4; ++nt)
        #pragma unroll
        for (int r = 0; r < 4; ++r) {
          int lrow = s * 16 + quad * 4 + r;
          int gc   = w * 64 + nt * 16 + l16;
          float ccv = (float)cc[s][nt][r >> 1][r & 1];
          float tv  = fast_tanh(acc[s][nt][r] + ccv);
          float h5  = 0.5f * (float)hr[s][nt][r >> 1][r & 1] + 0.5f * tv;
          float hnew;
          if (!lastS) {
            hnew = h5;
          } else {
            float ee = (float)eeL[lrow * 512 + gc];
            float cn = 0.5f * ccv + 0.5f * h5 + ee;
            cc[s][nt][r >> 1][r & 1] = (_Float16)cn;
            hnew = 0.5f * fast_tanh(cn);  // folded hh1 of next outer step
          }
          hr[s][nt][r >> 1][r & 1] = (_Float16)hnew;
          int phys = (gc >> 3) ^ (lrow & 7);
          hhL[lrow * 512 + phys * 8 + (gc & 7)] = (_Float16)hnew;
        }
    __syncthreads();  // bar2: writes visible
  }

  // Final h = cc - 2*ee -> hhL (swizzled) -> coalesced global store
  #pragma unroll
  for (int s = 0; s < 2; ++s)
    #pragma unroll
    for (int nt = 0; nt < 4; ++nt)
      #pragma unroll
      for (int r = 0; r < 4; ++r) {
        int lrow = s * 16 + quad * 4 + r;
        int gc   = w * 64 + nt * 16 + l16;
        float hv = (float)cc[s][nt][r >> 1][r & 1] -
                   2.0f * (float)eeL[lrow * 512 + gc];
        int phys = (gc >> 3) ^ (lrow & 7);
        hhL[lrow * 512 + phys * 8 + (gc & 7)] = (_Float16)hv;
      }
  __syncthreads();
  #pragma unroll
  for (int i = 0; i < 4; ++i) {
    int q = tid + 512 * i;             // 2048 chunks of 8 f16
    int lrow = q >> 6, c = q & 63;
    int phys = c ^ (lrow & 7);
    int grow = row0 + (lrow >> 4) * 4096 + (lrow & 15);
    *reinterpret_cast<uint4*>(&hg[(size_t)grow * 512 + c * 8]) =
        *reinterpret_cast<const uint4*>(&hhL[lrow * 512 + phys * 8]);
  }
}

// ---------------------------------------------------------------------------
// Launch
// ---------------------------------------------------------------------------
extern "C" void kernel_launch(void* const* d_in, const int* in_sizes, int n_in,
                              void* d_out, int out_size, void* d_ws,
                              size_t ws_size, hipStream_t stream) {
  const float* x  = (const float*)d_in[0];
  const float* We = (const float*)d_in[1];
  const float* be = (const float*)d_in[2];
  const float* W  = (const float*)d_in[3];
  const float* bW = (const float*)d_in[4];
  const float* u  = (const float*)d_in[5];
  const float* Wh = (const float*)d_in[6];
  const float* bh = (const float*)d_in[7];
  float* out = (float*)d_out;

  char* ws = (char*)d_ws;
  size_t off = 0;
  auto alloc = [&](size_t bytes) -> char* {
    char* p = ws + off;
    off += (bytes + 255) & ~(size_t)255;
    return p;
  };
  _Float16* x_h  = (_Float16*)alloc((size_t)BATCH * DIN * 2);
  _Float16* We_h = (_Float16*)alloc((size_t)DH * DIN * 2);
  _Float16* Wf   = (_Float16*)alloc((size_t)DH * DH * 2);
  _Float16* Wh_h = (_Float16*)alloc((size_t)DOUT * DH * 2);
  float* sigma   = (float*)alloc(256);
  float* vbuf    = (float*)alloc(DH * 4);
  float* c0      = (float*)alloc((size_t)BATCH * DH * 4);
  _Float16* h_h  = (_Float16*)alloc((size_t)BATCH * DH * 2);
  (void)ws_size; (void)in_sizes; (void)n_in; (void)out_size;

  const int NE_X = BATCH * DIN;
  const int NE_W = DH * DIN;

  hipMemsetAsync(vbuf, 0, DH * 4, stream);
  sigma_k1<<<64, 512, 0, stream>>>(W, u, vbuf);
  sigma_k2<<<1, 512, 0, stream>>>(W, vbuf, sigma);

  build_wf<<<128, 256, 0, stream>>>(W, sigma, Wf);
  f32_to_f16<<<(NE_X + 255) / 256, 256, 0, stream>>>(x, x_h, NE_X);
  f32_to_f16<<<(NE_W + 255) / 256, 256, 0, stream>>>(We, We_h, NE_W);
  f32_to_f16<<<(DH * DH + 255) / 256, 256, 0, stream>>>(Wh, Wh_h, DH * DH);

  dim3 gemm_grid(BATCH / TM, DH / TN);  // (64, 8)

  gemm_fused<MODE_EMBED><<<gemm_grid, 256, 0, stream>>>(x_h, We_h, DIN, be, bW, c0);
  recurrence_persistent<<<BATCH / 32, 512, 0, stream>>>(Wf, c0, h_h);
  gemm_fused<MODE_HEAD><<<gemm_grid, 256, 0, stream>>>(h_h, Wh_h, DH, bh, nullptr, out);
}

// Round 7
// 1686.639 us; speedup vs baseline: 1.7129x; 1.7129x over previous
//
#include <hip/hip_runtime.h>
#include <hip/hip_fp16.h>
#include <math.h>

constexpr int BATCH = 8192;
constexpr int DIN   = 1024;
constexpr int DH    = 512;
constexpr int DOUT  = 512;
constexpr int STEPS = 30;

typedef __attribute__((ext_vector_type(8))) _Float16 f16x8;   // 4 VGPRs
typedef __attribute__((ext_vector_type(2))) _Float16 f16x2_t; // 1 VGPR
typedef __attribute__((ext_vector_type(4))) float f32x4;

#define AS1 __attribute__((address_space(1)))
#define AS3 __attribute__((address_space(3)))
// s_waitcnt imm: vm lo[3:0], exp[6:4]=7 (no wait), lgkm[11:8]=15 (no wait)
#define VMCNT_IMM(n) (((n) & 15) | (7 << 4) | (15 << 8))

__device__ __forceinline__ float fast_tanh(float x) {
  return 1.0f - 2.0f / (1.0f + __expf(2.0f * x));
}

// ---------------------------------------------------------------------------
// Spectral norm (split for coalescing)
// ---------------------------------------------------------------------------
__global__ void sigma_k1(const float* __restrict__ W,
                         const float* __restrict__ u,
                         float* __restrict__ v) {
  const int j = threadIdx.x;           // 512
  const int i0 = blockIdx.x * 8;       // 64 blocks
  float acc = 0.0f;
  #pragma unroll
  for (int i = 0; i < 8; ++i) acc += W[(size_t)(i0 + i) * DH + j] * u[i0 + i];
  atomicAdd(&v[j], acc);
}

__device__ __forceinline__ float block_reduce_sum_512(float x, float* sred) {
  #pragma unroll
  for (int off = 32; off > 0; off >>= 1) x += __shfl_down(x, off, 64);
  int wave = threadIdx.x >> 6, lane = threadIdx.x & 63;
  if (lane == 0) sred[wave] = x;
  __syncthreads();
  float r = 0.0f;
  if (wave == 0) {
    r = (lane < 8) ? sred[lane] : 0.0f;
    #pragma unroll
    for (int off = 4; off > 0; off >>= 1) r += __shfl_down(r, off, 64);
    if (lane == 0) sred[0] = r;
  }
  __syncthreads();
  float res = sred[0];
  __syncthreads();
  return res;
}

__global__ void sigma_k2(const float* __restrict__ W,
                         const float* __restrict__ vg,
                         float* __restrict__ sigma_out) {
  __shared__ __align__(16) float v[DH];
  __shared__ float sred[8];
  const int j = threadIdx.x;  // 512
  float vj = vg[j];
  float nn = block_reduce_sum_512(vj * vj, sred);
  float inv = 1.0f / (sqrtf(nn) + 1e-12f);
  v[j] = vj;
  __syncthreads();
  const float4* R = (const float4*)(W + (size_t)j * DH);
  const float4* V = (const float4*)v;
  float s0 = 0.f, s1 = 0.f, s2 = 0.f, s3 = 0.f;
  for (int q = 0; q < DH / 4; q += 4) {
    float4 r0 = R[q], r1 = R[q + 1], r2 = R[q + 2], r3 = R[q + 3];
    float4 v0 = V[q], v1 = V[q + 1], v2 = V[q + 2], v3 = V[q + 3];
    s0 += r0.x * v0.x + r0.y * v0.y + r0.z * v0.z + r0.w * v0.w;
    s1 += r1.x * v1.x + r1.y * v1.y + r1.z * v1.z + r1.w * v1.w;
    s2 += r2.x * v2.x + r2.y * v2.y + r2.z * v2.z + r2.w * v2.w;
    s3 += r3.x * v3.x + r3.y * v3.y + r3.z * v3.z + r3.w * v3.w;
  }
  float wi = ((s0 + s1) + (s2 + s3)) * inv;
  float ww = block_reduce_sum_512(wi * wi, sred);
  if (j == 0) sigma_out[0] = ww / (sqrtf(ww) + 1e-12f);
}

__global__ void f32_to_f16(const float* __restrict__ in,
                           _Float16* __restrict__ out, int n) {
  int i = blockIdx.x * 256 + threadIdx.x;
  if (i < n) out[i] = (_Float16)in[i];
}

// Fragment-linear Wsn: Wf[g][kt][lane][j] = (W[n][k]/sigma) f16,
// n = g*16 + (lane&15), k = kt*32 + (lane>>4)*8 + j.  g<32, kt<16.
// Each (g,kt) slice is a contiguous 1 KB: exactly one wave-wide 16B/lane DMA.
__global__ void build_wf(const float* __restrict__ W,
                         const float* __restrict__ sigma,
                         _Float16* __restrict__ Wf) {
  int t = blockIdx.x * 256 + threadIdx.x;  // t < 32768
  int lane = t & 63, kt = (t >> 6) & 15, g = t >> 10;
  int n  = g * 16 + (lane & 15);
  int k0 = kt * 32 + (lane >> 4) * 8;
  float inv = 1.0f / sigma[0];
  #pragma unroll
  for (int j = 0; j < 8; ++j)
    Wf[(size_t)t * 8 + j] = (_Float16)(W[(size_t)n * DH + k0 + j] * inv);
}

// ---------------------------------------------------------------------------
// GEMM (embed / head) -- unchanged, working
// ---------------------------------------------------------------------------
#define TM 128
#define TN 64
#define BK 64
#define BKP (BK + 8)

enum { MODE_EMBED = 0, MODE_HEAD = 1 };

template <int MODE>
__global__ __launch_bounds__(256, 2) void gemm_fused(
    const _Float16* __restrict__ A, const _Float16* __restrict__ Bw, int K,
    const float* __restrict__ bias1, const float* __restrict__ bias2,
    float* __restrict__ outp) {
  __shared__ __align__(16) _Float16 As[TM][BKP];
  __shared__ __align__(16) _Float16 Bs[TN][BKP];
  const int tid = threadIdx.x, lane = tid & 63, wave = tid >> 6;
  const int wm = wave >> 1, wn = wave & 1;
  const int m0 = blockIdx.x * TM, n0 = blockIdx.y * TN;
  const int l16 = lane & 15, l4 = lane >> 4;

  f32x4 acc[4][2];
  #pragma unroll
  for (int i = 0; i < 4; ++i)
    #pragma unroll
    for (int j = 0; j < 2; ++j) acc[i][j] = (f32x4){0.f, 0.f, 0.f, 0.f};

  for (int k0 = 0; k0 < K; k0 += BK) {
    #pragma unroll
    for (int i = 0; i < 4; ++i) {
      int q = tid + 256 * i, row = q >> 3, col = (q & 7) * 8;
      *reinterpret_cast<uint4*>(&As[row][col]) =
          *reinterpret_cast<const uint4*>(&A[(size_t)(m0 + row) * K + k0 + col]);
    }
    #pragma unroll
    for (int i = 0; i < 2; ++i) {
      int q = tid + 256 * i, row = q >> 3, col = (q & 7) * 8;
      *reinterpret_cast<uint4*>(&Bs[row][col]) =
          *reinterpret_cast<const uint4*>(&Bw[(size_t)(n0 + row) * K + k0 + col]);
    }
    __syncthreads();
    #pragma unroll
    for (int s = 0; s < 2; ++s) {
      f16x8 afrag[4], bfrag[2];
      #pragma unroll
      for (int mi = 0; mi < 4; ++mi)
        afrag[mi] = *reinterpret_cast<const f16x8*>(
            &As[wm * 64 + mi * 16 + l16][s * 32 + l4 * 8]);
      #pragma unroll
      for (int ni = 0; ni < 2; ++ni)
        bfrag[ni] = *reinterpret_cast<const f16x8*>(
            &Bs[wn * 32 + ni * 16 + l16][s * 32 + l4 * 8]);
      #pragma unroll
      for (int mi = 0; mi < 4; ++mi)
        #pragma unroll
        for (int ni = 0; ni < 2; ++ni)
          acc[mi][ni] = __builtin_amdgcn_mfma_f32_16x16x32_f16(
              afrag[mi], bfrag[ni], acc[mi][ni], 0, 0, 0);
    }
    __syncthreads();
  }
  #pragma unroll
  for (int mi = 0; mi < 4; ++mi)
    #pragma unroll
    for (int ni = 0; ni < 2; ++ni)
      #pragma unroll
      for (int r = 0; r < 4; ++r) {
        int gm = m0 + wm * 64 + mi * 16 + l4 * 4 + r;
        int gn = n0 + wn * 32 + ni * 16 + l16;
        size_t idx = (size_t)gm * 512 + gn;
        float s = acc[mi][ni][r];
        outp[idx] = (MODE == MODE_EMBED) ? (s + bias1[gn] + bias2[gn])
                                         : (s + bias1[gn]);
      }
}

// ---------------------------------------------------------------------------
// Persistent recurrence with DEEP ASYNC WEIGHT STAGING.
// r4-r6 post-mortem: 23 us/step was Little's-law latency-bound -- only ~8
// weight loads in flight per wave (8 KB / ~700cyc = 13 B/cyc/CU). Fix: each
// wave DMAs its 4-tile kt-slice (4 KB = 4x global_load_lds width16) into a
// private 3-slot LDS ring -> 12 loads in flight/wave, 96/CU, paced by manual
// s_waitcnt vmcnt(8/4/0). Weights never touch VGPRs until ds_read_b128 just
// before the MFMA. LDS: hhL 32 KB + stage 8 waves x 12 KB = 128 KB static.
// ee(=0.5*c0) recomputed from c0g (global, L2-resident) every 4th step.
// ---------------------------------------------------------------------------
__global__ __launch_bounds__(512) void recurrence_persistent(
    const _Float16* __restrict__ Wf,   // [32][16][64][8] frag-linear f16
    const float* __restrict__ c0g,     // [8192][512] f32 (embed output)
    _Float16* __restrict__ hg)         // [8192][512] f16 (final h)
{
  __shared__ __align__(16) char smem[131072];  // 32 KB hhL + 96 KB stage ring
  _Float16* hhL = (_Float16*)smem;             // [32][512], XOR-swizzled
  const int tid  = threadIdx.x;
  const int lane = tid & 63;
  const int w    = tid >> 6;   // 0..7
  const int l16  = lane & 15;
  const int quad = lane >> 4;  // 0..3
  const int row0 = blockIdx.x * 16;  // stripe0; stripe1 = row0 + 4096

  // Wave-private stage ring: 3 slots x 4 KB
  char* stW = smem + 32768 + w * 12288;
  // Per-lane global source base for this wave's 4 tiles (tile i at +16 KB)
  const char* wfB = (const char*)Wf + (size_t)(4 * w) * 16384 + lane * 16;

  // Issue one kt-slice DMA (4 tiles x 1 KB) into slot s. LDS dst is
  // wave-uniform; HW scatters lane*16 [m104/m108].
  auto stage = [&](int kt, int s) {
    const char* g = wfB + kt * 1024;
    char* l = stW + s * 4096;
    #pragma unroll
    for (int i = 0; i < 4; ++i)
      __builtin_amdgcn_global_load_lds((const AS1 void*)(g + i * 16384),
                                       (AS3 void*)(l + i * 1024), 16, 0, 0);
  };

  // Init state: cc = c0, hh1 = 0.5 tanh(c0)  (ee = 0.5*c0 re-read later)
  f16x2_t cc[2][4][2], hr[2][4][2];
  #pragma unroll
  for (int s = 0; s < 2; ++s)
    #pragma unroll
    for (int nt = 0; nt < 4; ++nt)
      #pragma unroll
      for (int r = 0; r < 4; ++r) {
        int lrow = s * 16 + quad * 4 + r;
        int gc   = w * 64 + nt * 16 + l16;
        int grow = row0 + s * 4096 + quad * 4 + r;
        float c0 = c0g[(size_t)grow * 512 + gc];
        cc[s][nt][r >> 1][r & 1] = (_Float16)c0;
        float h1 = 0.5f * fast_tanh(c0);
        hr[s][nt][r >> 1][r & 1] = (_Float16)h1;
        int phys = (gc >> 3) ^ (lrow & 7);
        hhL[lrow * 512 + phys * 8 + (gc & 7)] = (_Float16)h1;
      }
  __syncthreads();

  // Prime the ring for step 0
  stage(0, 0); stage(1, 1); stage(2, 2);
  __asm__ volatile("" ::: "memory");

  // 120 GEMM-steps (30 outer x 4; inner step 1 folded since hh_0 = 0)
  #pragma unroll 1
  for (int step = 0; step < 4 * STEPS; ++step) {
    const bool lastS = (step & 3) == 3;
    f32x4 acc[2][4];
    #pragma unroll
    for (int s = 0; s < 2; ++s)
      #pragma unroll
      for (int nt = 0; nt < 4; ++nt) acc[s][nt] = (f32x4){0.f, 0.f, 0.f, 0.f};

    #pragma unroll
    for (int kt = 0; kt < 16; ++kt) {
      // Pace the DMA ring: slot kt%3 ready when <=8 (then 4, then 0) remain.
      if (kt <= 13)      __builtin_amdgcn_s_waitcnt(VMCNT_IMM(8));
      else if (kt == 14) __builtin_amdgcn_s_waitcnt(VMCNT_IMM(4));
      else               __builtin_amdgcn_s_waitcnt(VMCNT_IMM(0));
      __asm__ volatile("" ::: "memory");

      const _Float16* sl = (const _Float16*)(stW + (kt % 3) * 4096) + lane * 8;
      f16x8 b0 = *reinterpret_cast<const f16x8*>(sl);
      f16x8 b1 = *reinterpret_cast<const f16x8*>(sl + 512);
      f16x8 b2 = *reinterpret_cast<const f16x8*>(sl + 1024);
      f16x8 b3 = *reinterpret_cast<const f16x8*>(sl + 1536);
      #pragma unroll
      for (int s = 0; s < 2; ++s) {
        int lrow = s * 16 + l16;
        int phys = (kt * 4 + quad) ^ (l16 & 7);
        f16x8 af = *reinterpret_cast<const f16x8*>(&hhL[lrow * 512 + phys * 8]);
        acc[s][0] = __builtin_amdgcn_mfma_f32_16x16x32_f16(af, b0, acc[s][0], 0, 0, 0);
        acc[s][1] = __builtin_amdgcn_mfma_f32_16x16x32_f16(af, b1, acc[s][1], 0, 0, 0);
        acc[s][2] = __builtin_amdgcn_mfma_f32_16x16x32_f16(af, b2, acc[s][2], 0, 0, 0);
        acc[s][3] = __builtin_amdgcn_mfma_f32_16x16x32_f16(af, b3, acc[s][3], 0, 0, 0);
      }
      // Refill just-consumed slot with kt+3 (MFMAs above already forced
      // lgkm drain of this slot's ds_reads; DMA write lands >=400cyc later).
      if (kt < 13) {
        __asm__ volatile("" ::: "memory");
        stage(kt + 3, kt % 3);
      }
    }
    __syncthreads();  // bar1: all hhL reads complete

    // Prime ring for NEXT step (same weights) -- DMA overlaps the epilogue.
    __asm__ volatile("" ::: "memory");
    stage(0, 0); stage(1, 1); stage(2, 2);
    __asm__ volatile("" ::: "memory");

    // Epilogue + hh writes
    #pragma unroll
    for (int s = 0; s < 2; ++s)
      #pragma unroll
      for (int nt = 0; nt < 4; ++nt)
        #pragma unroll
        for (int r = 0; r < 4; ++r) {
          int lrow = s * 16 + quad * 4 + r;
          int gc   = w * 64 + nt * 16 + l16;
          float ccv = (float)cc[s][nt][r >> 1][r & 1];
          float tv  = fast_tanh(acc[s][nt][r] + ccv);
          float h5  = 0.5f * (float)hr[s][nt][r >> 1][r & 1] + 0.5f * tv;
          float hnew;
          if (!lastS) {
            hnew = h5;
          } else {
            int grow = row0 + s * 4096 + quad * 4 + r;
            float ee = 0.5f * c0g[(size_t)grow * 512 + gc];  // L2-resident
            float cn = 0.5f * ccv + 0.5f * h5 + ee;
            cc[s][nt][r >> 1][r & 1] = (_Float16)cn;
            hnew = 0.5f * fast_tanh(cn);  // folded hh1 of next outer step
          }
          hr[s][nt][r >> 1][r & 1] = (_Float16)hnew;
          int phys = (gc >> 3) ^ (lrow & 7);
          hhL[lrow * 512 + phys * 8 + (gc & 7)] = (_Float16)hnew;
        }
    __syncthreads();  // bar2: writes visible (also drains primed DMAs -> done)
  }

  // Final h = cc - 2*ee = cc - c0  -> hhL (swizzled) -> coalesced store
  #pragma unroll
  for (int s = 0; s < 2; ++s)
    #pragma unroll
    for (int nt = 0; nt < 4; ++nt)
      #pragma unroll
      for (int r = 0; r < 4; ++r) {
        int lrow = s * 16 + quad * 4 + r;
        int gc   = w * 64 + nt * 16 + l16;
        int grow = row0 + s * 4096 + quad * 4 + r;
        float hv = (float)cc[s][nt][r >> 1][r & 1] - c0g[(size_t)grow * 512 + gc];
        int phys = (gc >> 3) ^ (lrow & 7);
        hhL[lrow * 512 + phys * 8 + (gc & 7)] = (_Float16)hv;
      }
  __syncthreads();
  #pragma unroll
  for (int i = 0; i < 4; ++i) {
    int q = tid + 512 * i;             // 2048 chunks of 8 f16
    int lrow = q >> 6, c = q & 63;
    int phys = c ^ (lrow & 7);
    int grow = row0 + (lrow >> 4) * 4096 + (lrow & 15);
    *reinterpret_cast<uint4*>(&hg[(size_t)grow * 512 + c * 8]) =
        *reinterpret_cast<const uint4*>(&hhL[lrow * 512 + phys * 8]);
  }
}

// ---------------------------------------------------------------------------
// Launch
// ---------------------------------------------------------------------------
extern "C" void kernel_launch(void* const* d_in, const int* in_sizes, int n_in,
                              void* d_out, int out_size, void* d_ws,
                              size_t ws_size, hipStream_t stream) {
  const float* x  = (const float*)d_in[0];
  const float* We = (const float*)d_in[1];
  const float* be = (const float*)d_in[2];
  const float* W  = (const float*)d_in[3];
  const float* bW = (const float*)d_in[4];
  const float* u  = (const float*)d_in[5];
  const float* Wh = (const float*)d_in[6];
  const float* bh = (const float*)d_in[7];
  float* out = (float*)d_out;

  char* ws = (char*)d_ws;
  size_t off = 0;
  auto alloc = [&](size_t bytes) -> char* {
    char* p = ws + off;
    off += (bytes + 255) & ~(size_t)255;
    return p;
  };
  _Float16* x_h  = (_Float16*)alloc((size_t)BATCH * DIN * 2);
  _Float16* We_h = (_Float16*)alloc((size_t)DH * DIN * 2);
  _Float16* Wf   = (_Float16*)alloc((size_t)DH * DH * 2);
  _Float16* Wh_h = (_Float16*)alloc((size_t)DOUT * DH * 2);
  float* sigma   = (float*)alloc(256);
  float* vbuf    = (float*)alloc(DH * 4);
  float* c0      = (float*)alloc((size_t)BATCH * DH * 4);
  _Float16* h_h  = (_Float16*)alloc((size_t)BATCH * DH * 2);
  (void)ws_size; (void)in_sizes; (void)n_in; (void)out_size;

  const int NE_X = BATCH * DIN;
  const int NE_W = DH * DIN;

  hipMemsetAsync(vbuf, 0, DH * 4, stream);
  sigma_k1<<<64, 512, 0, stream>>>(W, u, vbuf);
  sigma_k2<<<1, 512, 0, stream>>>(W, vbuf, sigma);

  build_wf<<<128, 256, 0, stream>>>(W, sigma, Wf);
  f32_to_f16<<<(NE_X + 255) / 256, 256, 0, stream>>>(x, x_h, NE_X);
  f32_to_f16<<<(NE_W + 255) / 256, 256, 0, stream>>>(We, We_h, NE_W);
  f32_to_f16<<<(DH * DH + 255) / 256, 256, 0, stream>>>(Wh, Wh_h, DH * DH);

  dim3 gemm_grid(BATCH / TM, DH / TN);  // (64, 8)

  gemm_fused<MODE_EMBED><<<gemm_grid, 256, 0, stream>>>(x_h, We_h, DIN, be, bW, c0);
  recurrence_persistent<<<BATCH / 32, 512, 0, stream>>>(Wf, c0, h_h);
  gemm_fused<MODE_HEAD><<<gemm_grid, 256, 0, stream>>>(h_h, Wh_h, DH, bh, nullptr, out);
}

// Round 8
// 1604.087 us; speedup vs baseline: 1.8010x; 1.0515x over previous
//
#include <hip/hip_runtime.h>
#include <hip/hip_fp16.h>
#include <math.h>

constexpr int BATCH = 8192;
constexpr int DIN   = 1024;
constexpr int DH    = 512;
constexpr int DOUT  = 512;
constexpr int STEPS = 30;

typedef __attribute__((ext_vector_type(8))) _Float16 f16x8;   // 4 VGPRs
typedef __attribute__((ext_vector_type(2))) _Float16 f16x2_t; // 1 VGPR
typedef __attribute__((ext_vector_type(4))) float f32x4;

#define AS1 __attribute__((address_space(1)))
#define AS3 __attribute__((address_space(3)))
// s_waitcnt imm: vm lo[3:0], exp[6:4]=7 (no wait), lgkm[11:8]=15 (no wait)
#define VMCNT_IMM(n) (((n) & 15) | (7 << 4) | (15 << 8))

__device__ __forceinline__ float fast_tanh(float x) {
  return 1.0f - 2.0f / (1.0f + __expf(2.0f * x));
}

// ---------------------------------------------------------------------------
// Spectral norm (split for coalescing)
// ---------------------------------------------------------------------------
__global__ void sigma_k1(const float* __restrict__ W,
                         const float* __restrict__ u,
                         float* __restrict__ v) {
  const int j = threadIdx.x;           // 512
  const int i0 = blockIdx.x * 8;       // 64 blocks
  float acc = 0.0f;
  #pragma unroll
  for (int i = 0; i < 8; ++i) acc += W[(size_t)(i0 + i) * DH + j] * u[i0 + i];
  atomicAdd(&v[j], acc);
}

__device__ __forceinline__ float block_reduce_sum_512(float x, float* sred) {
  #pragma unroll
  for (int off = 32; off > 0; off >>= 1) x += __shfl_down(x, off, 64);
  int wave = threadIdx.x >> 6, lane = threadIdx.x & 63;
  if (lane == 0) sred[wave] = x;
  __syncthreads();
  float r = 0.0f;
  if (wave == 0) {
    r = (lane < 8) ? sred[lane] : 0.0f;
    #pragma unroll
    for (int off = 4; off > 0; off >>= 1) r += __shfl_down(r, off, 64);
    if (lane == 0) sred[0] = r;
  }
  __syncthreads();
  float res = sred[0];
  __syncthreads();
  return res;
}

__global__ void sigma_k2(const float* __restrict__ W,
                         const float* __restrict__ vg,
                         float* __restrict__ sigma_out) {
  __shared__ __align__(16) float v[DH];
  __shared__ float sred[8];
  const int j = threadIdx.x;  // 512
  float vj = vg[j];
  float nn = block_reduce_sum_512(vj * vj, sred);
  float inv = 1.0f / (sqrtf(nn) + 1e-12f);
  v[j] = vj;
  __syncthreads();
  const float4* R = (const float4*)(W + (size_t)j * DH);
  const float4* V = (const float4*)v;
  float s0 = 0.f, s1 = 0.f, s2 = 0.f, s3 = 0.f;
  for (int q = 0; q < DH / 4; q += 4) {
    float4 r0 = R[q], r1 = R[q + 1], r2 = R[q + 2], r3 = R[q + 3];
    float4 v0 = V[q], v1 = V[q + 1], v2 = V[q + 2], v3 = V[q + 3];
    s0 += r0.x * v0.x + r0.y * v0.y + r0.z * v0.z + r0.w * v0.w;
    s1 += r1.x * v1.x + r1.y * v1.y + r1.z * v1.z + r1.w * v1.w;
    s2 += r2.x * v2.x + r2.y * v2.y + r2.z * v2.z + r2.w * v2.w;
    s3 += r3.x * v3.x + r3.y * v3.y + r3.z * v3.z + r3.w * v3.w;
  }
  float wi = ((s0 + s1) + (s2 + s3)) * inv;
  float ww = block_reduce_sum_512(wi * wi, sred);
  if (j == 0) sigma_out[0] = ww / (sqrtf(ww) + 1e-12f);
}

__global__ void f32_to_f16(const float* __restrict__ in,
                           _Float16* __restrict__ out, int n) {
  int i = blockIdx.x * 256 + threadIdx.x;
  if (i < n) out[i] = (_Float16)in[i];
}

// Fragment-linear Wsn: Wf[g][kt][lane][j] = (W[n][k]/sigma) f16,
// n = g*16 + (lane&15), k = kt*32 + (lane>>4)*8 + j.  g<32, kt<16.
// Each (g,kt) slice is a contiguous 1 KB: exactly one wave-wide 16B/lane DMA.
__global__ void build_wf(const float* __restrict__ W,
                         const float* __restrict__ sigma,
                         _Float16* __restrict__ Wf) {
  int t = blockIdx.x * 256 + threadIdx.x;  // t < 32768
  int lane = t & 63, kt = (t >> 6) & 15, g = t >> 10;
  int n  = g * 16 + (lane & 15);
  int k0 = kt * 32 + (lane >> 4) * 8;
  float inv = 1.0f / sigma[0];
  #pragma unroll
  for (int j = 0; j < 8; ++j)
    Wf[(size_t)t * 8 + j] = (_Float16)(W[(size_t)n * DH + k0 + j] * inv);
}

// ---------------------------------------------------------------------------
// GEMM (embed / head) -- unchanged, working
// ---------------------------------------------------------------------------
#define TM 128
#define TN 64
#define BK 64
#define BKP (BK + 8)

enum { MODE_EMBED = 0, MODE_HEAD = 1 };

template <int MODE>
__global__ __launch_bounds__(256, 2) void gemm_fused(
    const _Float16* __restrict__ A, const _Float16* __restrict__ Bw, int K,
    const float* __restrict__ bias1, const float* __restrict__ bias2,
    float* __restrict__ outp) {
  __shared__ __align__(16) _Float16 As[TM][BKP];
  __shared__ __align__(16) _Float16 Bs[TN][BKP];
  const int tid = threadIdx.x, lane = tid & 63, wave = tid >> 6;
  const int wm = wave >> 1, wn = wave & 1;
  const int m0 = blockIdx.x * TM, n0 = blockIdx.y * TN;
  const int l16 = lane & 15, l4 = lane >> 4;

  f32x4 acc[4][2];
  #pragma unroll
  for (int i = 0; i < 4; ++i)
    #pragma unroll
    for (int j = 0; j < 2; ++j) acc[i][j] = (f32x4){0.f, 0.f, 0.f, 0.f};

  for (int k0 = 0; k0 < K; k0 += BK) {
    #pragma unroll
    for (int i = 0; i < 4; ++i) {
      int q = tid + 256 * i, row = q >> 3, col = (q & 7) * 8;
      *reinterpret_cast<uint4*>(&As[row][col]) =
          *reinterpret_cast<const uint4*>(&A[(size_t)(m0 + row) * K + k0 + col]);
    }
    #pragma unroll
    for (int i = 0; i < 2; ++i) {
      int q = tid + 256 * i, row = q >> 3, col = (q & 7) * 8;
      *reinterpret_cast<uint4*>(&Bs[row][col]) =
          *reinterpret_cast<const uint4*>(&Bw[(size_t)(n0 + row) * K + k0 + col]);
    }
    __syncthreads();
    #pragma unroll
    for (int s = 0; s < 2; ++s) {
      f16x8 afrag[4], bfrag[2];
      #pragma unroll
      for (int mi = 0; mi < 4; ++mi)
        afrag[mi] = *reinterpret_cast<const f16x8*>(
            &As[wm * 64 + mi * 16 + l16][s * 32 + l4 * 8]);
      #pragma unroll
      for (int ni = 0; ni < 2; ++ni)
        bfrag[ni] = *reinterpret_cast<const f16x8*>(
            &Bs[wn * 32 + ni * 16 + l16][s * 32 + l4 * 8]);
      #pragma unroll
      for (int mi = 0; mi < 4; ++mi)
        #pragma unroll
        for (int ni = 0; ni < 2; ++ni)
          acc[mi][ni] = __builtin_amdgcn_mfma_f32_16x16x32_f16(
              afrag[mi], bfrag[ni], acc[mi][ni], 0, 0, 0);
    }
    __syncthreads();
  }
  #pragma unroll
  for (int mi = 0; mi < 4; ++mi)
    #pragma unroll
    for (int ni = 0; ni < 2; ++ni)
      #pragma unroll
      for (int r = 0; r < 4; ++r) {
        int gm = m0 + wm * 64 + mi * 16 + l4 * 4 + r;
        int gn = n0 + wn * 32 + ni * 16 + l16;
        size_t idx = (size_t)gm * 512 + gn;
        float s = acc[mi][ni][r];
        outp[idx] = (MODE == MODE_EMBED) ? (s + bias1[gn] + bias2[gn])
                                         : (s + bias1[gn]);
      }
}

// ---------------------------------------------------------------------------
// Persistent recurrence v3. r7 post-mortem: FETCH collapsed 8x (DMA staging
// keeps Wf L2-resident) but 13.2 us/step remained: ~480 MB of epilogue c0g
// re-reads (L2-missing, evicting Wf), 2 barrier drains/step, and LDS traffic.
// r8 changes:
//  * ee = 0.5*c0 lives in 16 f16x2 REGISTERS -> zero c0g traffic in the loop.
//  * hhL double-buffered (2 x 32 KB) -> ONE barrier/step. Proof: step t reads
//    buf[t&1], writes buf[(t+1)&1]; any two waves are within one barrier of
//    each other, so concurrent access is always read-cur/write-next.
//  * 2-slot DMA ring (8 waves x 8 KB): slot kt%2 holds kt's 4-KB slice;
//    refill at kt targets kt+2; wait vmcnt(4) gives a 2-iteration (~350 cyc)
//    margin over ~250 cyc L2-hit latency. Next step's slots primed right
//    after the K-loop so DMA overlaps epilogue + barrier drain.
// LDS: 64 KB hhL dbuf + 64 KB ring = 128 KB. ~100 arch VGPRs + acc in AGPRs.
// ---------------------------------------------------------------------------
__global__ __launch_bounds__(512) void recurrence_persistent(
    const _Float16* __restrict__ Wf,   // [32][16][64][8] frag-linear f16
    const float* __restrict__ c0g,     // [8192][512] f32 (embed output)
    _Float16* __restrict__ hg)         // [8192][512] f16 (final h)
{
  __shared__ __align__(16) char smem[131072];  // 64 KB hhL dbuf + 64 KB ring
  _Float16* hhL = (_Float16*)smem;             // [2][32][512], XOR-swizzled
  const int tid  = threadIdx.x;
  const int lane = tid & 63;
  const int w    = tid >> 6;   // 0..7
  const int l16  = lane & 15;
  const int quad = lane >> 4;  // 0..3
  const int row0 = blockIdx.x * 16;  // stripe0; stripe1 = row0 + 4096

  // Wave-private stage ring: 2 slots x 4 KB
  char* stW = smem + 65536 + w * 8192;
  // Per-lane global source base for this wave's 4 tiles (tile i at +16 KB)
  const char* wfB = (const char*)Wf + (size_t)(4 * w) * 16384 + lane * 16;

  // One kt-slice DMA (4 tiles x 1 KB) into slot s (LDS dst wave-uniform,
  // HW scatters lane*16).
  auto stage = [&](int kt, int s) {
    const char* g = wfB + kt * 1024;
    char* l = stW + s * 4096;
    #pragma unroll
    for (int i = 0; i < 4; ++i)
      __builtin_amdgcn_global_load_lds((const AS1 void*)(g + i * 16384),
                                       (AS3 void*)(l + i * 1024), 16, 0, 0);
  };

  // Init state: cc = c0 (f16), ee = 0.5*c0 (f16 regs), hh1 = 0.5 tanh(c0)
  f16x2_t cc[2][4][2], hr[2][4][2], ee[2][4][2];
  #pragma unroll
  for (int s = 0; s < 2; ++s)
    #pragma unroll
    for (int nt = 0; nt < 4; ++nt)
      #pragma unroll
      for (int r = 0; r < 4; ++r) {
        int lrow = s * 16 + quad * 4 + r;
        int gc   = w * 64 + nt * 16 + l16;
        int grow = row0 + s * 4096 + quad * 4 + r;
        float c0 = c0g[(size_t)grow * 512 + gc];
        cc[s][nt][r >> 1][r & 1] = (_Float16)c0;
        ee[s][nt][r >> 1][r & 1] = (_Float16)(0.5f * c0);
        float h1 = 0.5f * fast_tanh(c0);
        hr[s][nt][r >> 1][r & 1] = (_Float16)h1;
        int phys = (gc >> 3) ^ (lrow & 7);
        hhL[lrow * 512 + phys * 8 + (gc & 7)] = (_Float16)h1;  // buf0
      }
  // Prime ring for step 0
  stage(0, 0); stage(1, 1);
  __asm__ volatile("" ::: "memory");
  __syncthreads();

  // 120 GEMM-steps (30 outer x 4; inner step 1 folded since hh_0 = 0)
  #pragma unroll 1
  for (int step = 0; step < 4 * STEPS; ++step) {
    const bool lastS = (step & 3) == 3;
    const int cur = (step & 1) * 16384, nxt = ((step + 1) & 1) * 16384;
    f32x4 acc[2][4];
    #pragma unroll
    for (int s = 0; s < 2; ++s)
      #pragma unroll
      for (int nt = 0; nt < 4; ++nt) acc[s][nt] = (f32x4){0.f, 0.f, 0.f, 0.f};

    #pragma unroll
    for (int kt = 0; kt < 16; ++kt) {
      // Slot kt%2 ready when <=4 outstanding (its refill was issued at kt-2).
      if (kt < 15) __builtin_amdgcn_s_waitcnt(VMCNT_IMM(4));
      else         __builtin_amdgcn_s_waitcnt(VMCNT_IMM(0));
      __asm__ volatile("" ::: "memory");

      const _Float16* sl = (const _Float16*)(stW + (kt & 1) * 4096) + lane * 8;
      f16x8 b0 = *reinterpret_cast<const f16x8*>(sl);
      f16x8 b1 = *reinterpret_cast<const f16x8*>(sl + 512);
      f16x8 b2 = *reinterpret_cast<const f16x8*>(sl + 1024);
      f16x8 b3 = *reinterpret_cast<const f16x8*>(sl + 1536);
      #pragma unroll
      for (int s = 0; s < 2; ++s) {
        int lrow = s * 16 + l16;
        int phys = (kt * 4 + quad) ^ (l16 & 7);
        f16x8 af = *reinterpret_cast<const f16x8*>(
            &hhL[cur + lrow * 512 + phys * 8]);
        acc[s][0] = __builtin_amdgcn_mfma_f32_16x16x32_f16(af, b0, acc[s][0], 0, 0, 0);
        acc[s][1] = __builtin_amdgcn_mfma_f32_16x16x32_f16(af, b1, acc[s][1], 0, 0, 0);
        acc[s][2] = __builtin_amdgcn_mfma_f32_16x16x32_f16(af, b2, acc[s][2], 0, 0, 0);
        acc[s][3] = __builtin_amdgcn_mfma_f32_16x16x32_f16(af, b3, acc[s][3], 0, 0, 0);
      }
      // Refill consumed slot with kt+2 (this slot's ds_reads drained by the
      // lgkm waits the compiler puts before the MFMAs; DMA lands >=200cyc on).
      if (kt < 14) {
        __asm__ volatile("" ::: "memory");
        stage(kt + 2, kt & 1);
      }
    }

    // Prime ring for NEXT step (same weights): overlaps epilogue + barrier.
    __asm__ volatile("" ::: "memory");
    stage(0, 0); stage(1, 1);
    __asm__ volatile("" ::: "memory");

    // Epilogue: advance state, write hh into the NEXT buffer.
    #pragma unroll
    for (int s = 0; s < 2; ++s)
      #pragma unroll
      for (int nt = 0; nt < 4; ++nt)
        #pragma unroll
        for (int r = 0; r < 4; ++r) {
          int lrow = s * 16 + quad * 4 + r;
          int gc   = w * 64 + nt * 16 + l16;
          float ccv = (float)cc[s][nt][r >> 1][r & 1];
          float tv  = fast_tanh(acc[s][nt][r] + ccv);
          float h5  = 0.5f * (float)hr[s][nt][r >> 1][r & 1] + 0.5f * tv;
          float hnew;
          if (!lastS) {
            hnew = h5;
          } else {
            float cn = 0.5f * ccv + 0.5f * h5 + (float)ee[s][nt][r >> 1][r & 1];
            cc[s][nt][r >> 1][r & 1] = (_Float16)cn;
            hnew = 0.5f * fast_tanh(cn);  // folded hh1 of next outer step
          }
          hr[s][nt][r >> 1][r & 1] = (_Float16)hnew;
          int phys = (gc >> 3) ^ (lrow & 7);
          hhL[nxt + lrow * 512 + phys * 8 + (gc & 7)] = (_Float16)hnew;
        }
    __syncthreads();  // single barrier per step
  }

  // Final h = cc - 2*ee -> hhL buf0 (swizzled) -> coalesced global store
  #pragma unroll
  for (int s = 0; s < 2; ++s)
    #pragma unroll
    for (int nt = 0; nt < 4; ++nt)
      #pragma unroll
      for (int r = 0; r < 4; ++r) {
        int lrow = s * 16 + quad * 4 + r;
        int gc   = w * 64 + nt * 16 + l16;
        float hv = (float)cc[s][nt][r >> 1][r & 1] -
                   2.0f * (float)ee[s][nt][r >> 1][r & 1];
        int phys = (gc >> 3) ^ (lrow & 7);
        hhL[lrow * 512 + phys * 8 + (gc & 7)] = (_Float16)hv;
      }
  __syncthreads();
  #pragma unroll
  for (int i = 0; i < 4; ++i) {
    int q = tid + 512 * i;             // 2048 chunks of 8 f16
    int lrow = q >> 6, c = q & 63;
    int phys = c ^ (lrow & 7);
    int grow = row0 + (lrow >> 4) * 4096 + (lrow & 15);
    *reinterpret_cast<uint4*>(&hg[(size_t)grow * 512 + c * 8]) =
        *reinterpret_cast<const uint4*>(&hhL[lrow * 512 + phys * 8]);
  }
}

// ---------------------------------------------------------------------------
// Launch
// ---------------------------------------------------------------------------
extern "C" void kernel_launch(void* const* d_in, const int* in_sizes, int n_in,
                              void* d_out, int out_size, void* d_ws,
                              size_t ws_size, hipStream_t stream) {
  const float* x  = (const float*)d_in[0];
  const float* We = (const float*)d_in[1];
  const float* be = (const float*)d_in[2];
  const float* W  = (const float*)d_in[3];
  const float* bW = (const float*)d_in[4];
  const float* u  = (const float*)d_in[5];
  const float* Wh = (const float*)d_in[6];
  const float* bh = (const float*)d_in[7];
  float* out = (float*)d_out;

  char* ws = (char*)d_ws;
  size_t off = 0;
  auto alloc = [&](size_t bytes) -> char* {
    char* p = ws + off;
    off += (bytes + 255) & ~(size_t)255;
    return p;
  };
  _Float16* x_h  = (_Float16*)alloc((size_t)BATCH * DIN * 2);
  _Float16* We_h = (_Float16*)alloc((size_t)DH * DIN * 2);
  _Float16* Wf   = (_Float16*)alloc((size_t)DH * DH * 2);
  _Float16* Wh_h = (_Float16*)alloc((size_t)DOUT * DH * 2);
  float* sigma   = (float*)alloc(256);
  float* vbuf    = (float*)alloc(DH * 4);
  float* c0      = (float*)alloc((size_t)BATCH * DH * 4);
  _Float16* h_h  = (_Float16*)alloc((size_t)BATCH * DH * 2);
  (void)ws_size; (void)in_sizes; (void)n_in; (void)out_size;

  const int NE_X = BATCH * DIN;
  const int NE_W = DH * DIN;

  hipMemsetAsync(vbuf, 0, DH * 4, stream);
  sigma_k1<<<64, 512, 0, stream>>>(W, u, vbuf);
  sigma_k2<<<1, 512, 0, stream>>>(W, vbuf, sigma);

  build_wf<<<128, 256, 0, stream>>>(W, sigma, Wf);
  f32_to_f16<<<(NE_X + 255) / 256, 256, 0, stream>>>(x, x_h, NE_X);
  f32_to_f16<<<(NE_W + 255) / 256, 256, 0, stream>>>(We, We_h, NE_W);
  f32_to_f16<<<(DH * DH + 255) / 256, 256, 0, stream>>>(Wh, Wh_h, DH * DH);

  dim3 gemm_grid(BATCH / TM, DH / TN);  // (64, 8)

  gemm_fused<MODE_EMBED><<<gemm_grid, 256, 0, stream>>>(x_h, We_h, DIN, be, bW, c0);
  recurrence_persistent<<<BATCH / 32, 512, 0, stream>>>(Wf, c0, h_h);
  gemm_fused<MODE_HEAD><<<gemm_grid, 256, 0, stream>>>(h_h, Wh_h, DH, bh, nullptr, out);
}